// Round 8
// baseline (186.502 us; speedup 1.0000x reference)
//
#include <hip/hip_runtime.h>
#include <cfloat>

constexpr int NB   = 65;      // N_BINS (= OUTPUT_SIZE)
constexpr int LROW = 8192;    // L
constexpr int NT   = 512;     // threads per block
constexpr int EPT  = 16;      // elements per thread
constexpr int NBUK = 1024;    // value buckets for multiselect

// Monotone bucket map: v -> [0, NBUK). Equal v -> equal bucket. Clamping is
// monotone, so correctness never depends on the [-6,6] range assumption.
__device__ __forceinline__ int bucket_of(float v) {
    float t = (v + 6.0f) * (float(NBUK) / 12.0f);
    t = fminf(fmaxf(t, 0.0f), float(NBUK - 1));
    return (int)t;
}

__global__ __launch_bounds__(NT, 8) void mtf_kernel(const float* __restrict__ x,
                                                    float* __restrict__ out) {
    __shared__ __align__(16) float vals[LROW];          // 32 KB: bucket-grouped; later aliased as transition hist
    __shared__ __align__(16) unsigned int arr[NBUK + 1];// counts -> excl prefix -> incl ends -> edge-LUT L[]
    __shared__ unsigned int tops[64];                   // arr[16i+15]: level-1 for 64-ary search
    __shared__ float edges[NB];
    __shared__ unsigned short ebuk[NB];                 // bucket of each edge (sorted)
    __shared__ unsigned int wsum[8];
    __shared__ int wfirst[8];                           // per-wave lane-0 first bin
    __shared__ int s_first, s_last;

    const int row  = blockIdx.x;          // n*C + c
    const int tid  = threadIdx.x;
    const int lane = tid & 63;
    const int wid  = tid >> 6;
    const float* __restrict__ xr = x + (size_t)row * LROW;

    if (tid == 0) { s_first = LROW; s_last = -1; }
    #pragma unroll
    for (int q = 0; q < NBUK / NT; ++q) arr[tid + q * NT] = 0u;

    // ---- load 16 contiguous elements; cache value-bucket per element ----
    float v[EPT];
    int   bk[EPT];
    const int base = tid * EPT;
    #pragma unroll
    for (int q = 0; q < 4; ++q) {
        float4 t = *reinterpret_cast<const float4*>(xr + base + q * 4);
        v[q*4+0] = t.x; v[q*4+1] = t.y; v[q*4+2] = t.z; v[q*4+3] = t.w;
    }
    #pragma unroll
    for (int u = 0; u < EPT; ++u) bk[u] = bucket_of(v[u]);

    // ---- first/last nonzero: thread -> wave-reduce -> one atomic per wave ----
    int lfirst = LROW, llast = -1;
    #pragma unroll
    for (int u = 0; u < EPT; ++u)
        if (v[u] != 0.0f) { lfirst = min(lfirst, base + u); llast = max(llast, base + u); }
    #pragma unroll
    for (int d = 32; d > 0; d >>= 1) {
        lfirst = min(lfirst, __shfl_xor(lfirst, d));
        llast  = max(llast,  __shfl_xor(llast,  d));
    }
    __syncthreads();                      // init visible before atomics
    if (lane == 0 && llast >= 0) { atomicMin(&s_first, lfirst); atomicMax(&s_last, llast); }
    __syncthreads();
    const int first = s_first, last = s_last;
    const int m = (last >= 0) ? (last - first + 1) : 0;   // mask.sum()

    // ---- bucket counts (masked elements never placed; ranks only reach m-1) ----
    if (m > 0) {
        #pragma unroll
        for (int u = 0; u < EPT; ++u) {
            int idx = base + u;
            if (idx >= first && idx <= last) atomicAdd(&arr[bk[u]], 1u);
        }
    }
    __syncthreads();

    // ---- in-place exclusive scan of arr[0..NBUK) (2 counters/thread) ----
    {
        uint2 c = *reinterpret_cast<uint2*>(&arr[tid * 2]);
        unsigned own = c.x + c.y;
        unsigned inc = own;
        #pragma unroll
        for (int d = 1; d < 64; d <<= 1) {
            unsigned n = __shfl_up(inc, d);
            if (lane >= d) inc += n;
        }
        if (lane == 63) wsum[wid] = inc;
        __syncthreads();
        if (wid == 0) {                   // wave-parallel 8-element exclusive scan
            unsigned t0 = (lane < 8) ? wsum[lane] : 0u;
            unsigned sc = t0;
            #pragma unroll
            for (int d = 1; d < 8; d <<= 1) {
                unsigned n = __shfl_up(sc, d);
                if (lane >= d) sc += n;
            }
            if (lane < 8) wsum[lane] = sc - t0;
        }
        __syncthreads();
        unsigned b0 = wsum[wid] + (inc - own);
        arr[tid*2+0] = b0;
        arr[tid*2+1] = b0 + c.x;
    }
    __syncthreads();

    // ---- scatter: atomic-consume prefix -> arr becomes inclusive bucket ends ----
    if (m > 0) {
        #pragma unroll
        for (int u = 0; u < EPT; ++u) {
            int idx = base + u;
            if (idx >= first && idx <= last) {
                unsigned slot = atomicAdd(&arr[bk[u]], 1u);
                vals[slot] = v[u];
            }
        }
    }
    __syncthreads();
    if (tid < 64) tops[tid] = arr[tid * 16 + 15];   // level-1 search table
    __syncthreads();

    // ---- edges: ONE WAVE PER EDGE (wave-parallel selection) ----
    // jnp.linspace(0,1,66): delta = fl(1/65); qlev[k] = fl(k*delta).
    // pos = qlev*(m-1); frac = pos-floor(pos); q = vlo + frac*(vhi-vlo)
    // -- separate round-to-nearest f32 ops, no FMA contraction.
    for (int k = wid; k < NB; k += 8) {
        if (m == 0) {
            if (lane == 0) { edges[k] = 0.0f; ebuk[k] = (unsigned short)bucket_of(0.0f); }
            continue;
        }
        const float delta = __fdiv_rn(1.0f, 65.0f);
        float qv   = __fmul_rn((float)k, delta);
        float pos  = __fmul_rn(qv, (float)(m - 1));
        float flo  = floorf(pos);
        float frac = __fsub_rn(pos, flo);
        int lo = (int)flo;
        int hi = (int)ceilf(pos);

        // two-level 64-ary search: smallest b with arr[b] > r (arr = incl ends)
        int bL, bH;
        {
            unsigned long long b1 = __ballot((int)tops[lane] > lo);
            int seg = __ffsll(b1) - 1;                      // tops[63]=m>lo: nonzero
            unsigned long long b2 = __ballot(lane < 16 && (int)arr[seg*16 + lane] > lo);
            bL = seg * 16 + __ffsll(b2) - 1;
        }
        if (hi == lo) bH = bL;
        else {
            unsigned long long b1 = __ballot((int)tops[lane] > hi);
            int seg = __ffsll(b1) - 1;
            unsigned long long b2 = __ballot(lane < 16 && (int)arr[seg*16 + lane] > hi);
            bH = seg * 16 + __ffsll(b2) - 1;
        }

        int stL = bL ? (int)arr[bL - 1] : 0;
        int enL = (int)arr[bL];
        int rlo = lo - stL, rhi = hi - stL;
        bool sameB = (bH == bL);
        float vlo = 0.0f, vhi = 0.0f;
        bool fL = false, fH = !sameB;
        // counting selection: lane = candidate; inner loop is LDS broadcast
        for (int b0 = stL; b0 < enL; b0 += 64) {
            int i = b0 + lane;
            bool act = i < enL;
            float vi = act ? vals[i] : 0.0f;
            int cl = 0, ce = 0;
            for (int j = stL; j < enL; ++j) {
                float vj = vals[j];
                cl += (vj < vi);
                ce += (vj == vi);
            }
            if (!fL) {
                unsigned long long mk = __ballot(act && cl <= rlo && rlo < cl + ce);
                if (mk) { vlo = __shfl(vi, __ffsll(mk) - 1); fL = true; }
            }
            if (!fH) {
                unsigned long long mk = __ballot(act && cl <= rhi && rhi < cl + ce);
                if (mk) { vhi = __shfl(vi, __ffsll(mk) - 1); fH = true; }
            }
            if (fL && fH) break;
        }
        if (!sameB) {
            // hi's in-bucket rank is 0 by prefix continuity -> bucket minimum
            int stH = (int)arr[bH - 1], enH = (int)arr[bH];   // bH > bL >= 0
            float mn = FLT_MAX;
            for (int i = stH + lane; i < enH; i += 64) mn = fminf(mn, vals[i]);
            #pragma unroll
            for (int d = 32; d > 0; d >>= 1) mn = fminf(mn, __shfl_xor(mn, d));
            vhi = mn;
        }
        float e = __fadd_rn(vlo, __fmul_rn(frac, __fsub_rn(vhi, vlo)));
        if (lane == 0) { edges[k] = e; ebuk[k] = (unsigned short)bucket_of(e); }
    }
    __syncthreads();

    // ---- build L[b] = #edges in buckets < b (arr dead -> reuse as LUT);
    //      zero the transition hist (vals dead -> alias) in the same phase ----
    unsigned int* thist = reinterpret_cast<unsigned int*>(vals);
    for (int i = tid; i < NB * NB; i += NT) thist[i] = 0u;
    for (int b = tid; b <= NBUK; b += NT) {
        int lo2 = 0, hi2 = NB;                // lower_bound(ebuk, b)
        #pragma unroll
        for (int it = 0; it < 7; ++it) {      // ceil(log2(66)) = 7
            if (lo2 < hi2) {
                int mid = (lo2 + hi2) >> 1;
                if ((int)ebuk[mid] < b) lo2 = mid + 1; else hi2 = mid;
            }
        }
        arr[b] = (unsigned)lo2;
    }
    __syncthreads();

    // ---- bin all elements via bucket LUT:
    //      edges in buckets < bk are <= v; in buckets > bk are > v;
    //      only edges sharing v's bucket need comparing ----
    int bl[EPT];
    #pragma unroll
    for (int u = 0; u < EPT; ++u) {
        int b   = bk[u];
        int cnt = (int)arr[b];
        int en  = (int)arr[b + 1];
        for (int j = cnt; j < en; ++j) cnt += (edges[j] <= v[u]);
        bl[u] = min(cnt, NB - 1);
    }
    if (lane == 0) wfirst[wid] = bl[0];
    __syncthreads();

    // ---- transition histogram over 8191 consecutive pairs ----
    int nxt0 = __shfl_down(bl[0], 1);             // next thread's first bin
    if (lane == 63 && wid < 7) nxt0 = wfirst[wid + 1];
    #pragma unroll
    for (int u = 0; u + 1 < EPT; ++u)
        atomicAdd(&thist[bl[u] * NB + bl[u + 1]], 1u);
    if (tid + 1 < NT)
        atomicAdd(&thist[bl[EPT - 1] * NB + nxt0], 1u);
    __syncthreads();

    // ---- write out: hist / (L-1) ----
    float* __restrict__ orow = out + (size_t)row * (NB * NB);
    for (int i = tid; i < NB * NB; i += NT)
        orow[i] = __fdiv_rn((float)thist[i], (float)(LROW - 1));
}

extern "C" void kernel_launch(void* const* d_in, const int* in_sizes, int n_in,
                              void* d_out, int out_size, void* d_ws, size_t ws_size,
                              hipStream_t stream) {
    const float* x = (const float*)d_in[0];
    float* out = (float*)d_out;
    const int rows = in_sizes[0] / LROW;   // N*C = 2048
    mtf_kernel<<<rows, NT, 0, stream>>>(x, out);
}

// Round 9
// 174.066 us; speedup vs baseline: 1.0714x; 1.0714x over previous
//
#include <hip/hip_runtime.h>
#include <cfloat>

constexpr int NB   = 65;      // N_BINS (= OUTPUT_SIZE)
constexpr int LROW = 8192;    // L
constexpr int NT   = 512;     // threads per block
constexpr int EPT  = 16;      // elements per thread
constexpr int NBUK = 1024;    // value buckets for multiselect

// Monotone bucket map: v -> [0, NBUK). Equal v -> equal bucket. Clamping is
// monotone, so correctness never depends on the [-6,6] range assumption.
// ~4 VALU; ALWAYS recompute (caching 16 of these spilled to scratch in r8).
__device__ __forceinline__ int bucket_of(float v) {
    float t = (v + 6.0f) * (float(NBUK) / 12.0f);
    t = fminf(fmaxf(t, 0.0f), float(NBUK - 1));
    return (int)t;
}

struct ERange { unsigned short stL, enL, stH, enH; };   // pre-scatter bucket ranges

__global__ __launch_bounds__(NT, 8) void mtf_kernel(const float* __restrict__ x,
                                                    float* __restrict__ out) {
    __shared__ __align__(16) float vals[LROW];          // 32 KB: interesting-bucket values; later aliased as hist
    __shared__ __align__(16) unsigned int arr[NBUK + 1];// counts -> excl prefix (arr[NBUK]=m) -> consumed -> edge LUT
    __shared__ unsigned int tops[64];                   // arr[16i+16]: level-1 for 64-ary rank search
    __shared__ float edges[NB];
    __shared__ unsigned short ebuk[NB];                 // bucket of each edge (sorted)
    __shared__ ERange erng[NB];                         // per-edge bucket ranges (recorded pre-scatter)
    __shared__ unsigned int bmap[NBUK / 32];            // interesting-bucket bitmap
    __shared__ unsigned int wsum[8];
    __shared__ int wfirst[8];
    __shared__ int s_first, s_last;

    const int row  = blockIdx.x;          // n*C + c
    const int tid  = threadIdx.x;
    const int lane = tid & 63;
    const int wid  = tid >> 6;
    const float* __restrict__ xr = x + (size_t)row * LROW;

    if (tid == 0) { s_first = LROW; s_last = -1; }
    #pragma unroll
    for (int q = 0; q < NBUK / NT; ++q) arr[tid + q * NT] = 0u;
    if (tid < NBUK / 32) bmap[tid] = 0u;

    // ---- load 16 contiguous elements into registers ----
    float v[EPT];
    const int base = tid * EPT;
    #pragma unroll
    for (int q = 0; q < 4; ++q) {
        float4 t = *reinterpret_cast<const float4*>(xr + base + q * 4);
        v[q*4+0] = t.x; v[q*4+1] = t.y; v[q*4+2] = t.z; v[q*4+3] = t.w;
    }

    // ---- first/last nonzero: thread -> wave-reduce -> one atomic per wave ----
    int lfirst = LROW, llast = -1;
    #pragma unroll
    for (int u = 0; u < EPT; ++u)
        if (v[u] != 0.0f) { lfirst = min(lfirst, base + u); llast = max(llast, base + u); }
    #pragma unroll
    for (int d = 32; d > 0; d >>= 1) {
        lfirst = min(lfirst, __shfl_xor(lfirst, d));
        llast  = max(llast,  __shfl_xor(llast,  d));
    }
    __syncthreads();                      // init visible before atomics
    if (lane == 0 && llast >= 0) { atomicMin(&s_first, lfirst); atomicMax(&s_last, llast); }
    __syncthreads();
    const int first = s_first, last = s_last;
    const int m = (last >= 0) ? (last - first + 1) : 0;   // mask.sum()

    // ---- bucket counts (masked elements never placed; ranks only reach m-1) ----
    if (m > 0) {
        #pragma unroll
        for (int u = 0; u < EPT; ++u) {
            int idx = base + u;
            if (idx >= first && idx <= last) atomicAdd(&arr[bucket_of(v[u])], 1u);
        }
    }
    __syncthreads();

    // ---- in-place exclusive scan of arr[0..NBUK); arr[NBUK]=m ----
    {
        uint2 c = *reinterpret_cast<uint2*>(&arr[tid * 2]);
        unsigned own = c.x + c.y;
        unsigned inc = own;
        #pragma unroll
        for (int d = 1; d < 64; d <<= 1) {
            unsigned n = __shfl_up(inc, d);
            if (lane >= d) inc += n;
        }
        if (lane == 63) wsum[wid] = inc;
        __syncthreads();
        if (wid == 0) {
            unsigned t0 = (lane < 8) ? wsum[lane] : 0u;
            unsigned sc = t0;
            #pragma unroll
            for (int d = 1; d < 8; d <<= 1) {
                unsigned n = __shfl_up(sc, d);
                if (lane >= d) sc += n;
            }
            if (lane < 8) wsum[lane] = sc - t0;
        }
        __syncthreads();
        unsigned b0 = wsum[wid] + (inc - own);
        arr[tid*2+0] = b0;
        arr[tid*2+1] = b0 + c.x;
        if (tid == NT - 1) arr[NBUK] = b0 + own;          // total = m
    }
    __syncthreads();
    if (tid < 64) tops[tid] = arr[tid * 16 + 16];         // ends of bucket 16i+15
    __syncthreads();

    // ---- E1: rank->bucket searches on the PREFIX array; record ranges;
    //      mark interesting buckets (ranks depend only on m) ----
    const float delta = __fdiv_rn(1.0f, 65.0f);           // fl(1/65), matches linspace
    for (int k = wid; k < NB; k += 8) {
        if (m == 0) continue;
        float qv  = __fmul_rn((float)k, delta);
        float pos = __fmul_rn(qv, (float)(m - 1));
        int lo = (int)floorf(pos);
        int hi = (int)ceilf(pos);
        // smallest b with prefix[b+1] > r  (element of rank r lives in b)
        int bL, bH;
        {
            unsigned long long b1 = __ballot((int)tops[lane] > lo);  // tops[63]=m>lo
            int seg = __ffsll(b1) - 1;
            unsigned long long b2 = __ballot(lane < 16 && (int)arr[seg*16 + lane + 1] > lo);
            bL = seg * 16 + __ffsll(b2) - 1;
        }
        if (hi == lo) bH = bL;
        else {
            unsigned long long b1 = __ballot((int)tops[lane] > hi);
            int seg = __ffsll(b1) - 1;
            unsigned long long b2 = __ballot(lane < 16 && (int)arr[seg*16 + lane + 1] > hi);
            bH = seg * 16 + __ffsll(b2) - 1;
        }
        if (lane == 0) {
            ERange e;
            e.stL = (unsigned short)arr[bL]; e.enL = (unsigned short)arr[bL + 1];
            e.stH = (unsigned short)arr[bH]; e.enH = (unsigned short)arr[bH + 1];
            erng[k] = e;
            atomicOr(&bmap[bL >> 5], 1u << (bL & 31));
            atomicOr(&bmap[bH >> 5], 1u << (bH & 31));
        }
    }
    __syncthreads();

    // ---- sparse scatter: only elements in interesting buckets (~10-15%) ----
    if (m > 0) {
        #pragma unroll
        for (int u = 0; u < EPT; ++u) {
            int idx = base + u;
            if (idx >= first && idx <= last) {
                int b = bucket_of(v[u]);
                if ((bmap[b >> 5] >> (b & 31)) & 1u) {
                    unsigned slot = atomicAdd(&arr[b], 1u);   // consume prefix
                    vals[slot] = v[u];
                }
            }
        }
    }
    __syncthreads();

    // ---- E2: wave-parallel counting selection in recorded ranges ----
    // q = vlo + frac*(vhi-vlo): separate _rn ops, no FMA (matches JAX f32).
    for (int k = wid; k < NB; k += 8) {
        if (m == 0) {
            if (lane == 0) { edges[k] = 0.0f; ebuk[k] = (unsigned short)bucket_of(0.0f); }
            continue;
        }
        float qv   = __fmul_rn((float)k, delta);
        float pos  = __fmul_rn(qv, (float)(m - 1));
        float flo  = floorf(pos);
        float frac = __fsub_rn(pos, flo);
        int lo = (int)flo;
        int hi = (int)ceilf(pos);
        ERange e = erng[k];
        int stL = e.stL, enL = e.enL;
        int rlo = lo - stL, rhi = hi - stL;
        bool sameB = (e.stH == e.stL);        // bH==bL  (bL nonempty => ranges differ otherwise)
        float vlo = 0.0f, vhi = 0.0f;
        bool fL = false, fH = !sameB;
        for (int b0 = stL; b0 < enL; b0 += 64) {
            int i = b0 + lane;
            bool act = i < enL;
            float vi = act ? vals[i] : 0.0f;
            int cl = 0, ce = 0;
            for (int j = stL; j < enL; ++j) {  // LDS broadcast reads
                float vj = vals[j];
                cl += (vj < vi);
                ce += (vj == vi);
            }
            if (!fL) {
                unsigned long long mk = __ballot(act && cl <= rlo && rlo < cl + ce);
                if (mk) { vlo = __shfl(vi, __ffsll(mk) - 1); fL = true; }
            }
            if (!fH) {
                unsigned long long mk = __ballot(act && cl <= rhi && rhi < cl + ce);
                if (mk) { vhi = __shfl(vi, __ffsll(mk) - 1); fH = true; }
            }
            if (fL && fH) break;
        }
        if (!sameB) {
            // hi's in-bucket rank is 0 by prefix continuity -> bucket minimum
            float mn = FLT_MAX;
            for (int i = e.stH + lane; i < e.enH; i += 64) mn = fminf(mn, vals[i]);
            #pragma unroll
            for (int d = 32; d > 0; d >>= 1) mn = fminf(mn, __shfl_xor(mn, d));
            vhi = mn;
        }
        float ev = __fadd_rn(vlo, __fmul_rn(frac, __fsub_rn(vhi, vlo)));
        if (lane == 0) { edges[k] = ev; ebuk[k] = (unsigned short)bucket_of(ev); }
    }
    __syncthreads();

    // ---- build L[b] = #edges in buckets < b (arr dead -> reuse);
    //      zero the transition hist (vals dead -> alias) ----
    unsigned int* thist = reinterpret_cast<unsigned int*>(vals);
    for (int i = tid; i < NB * NB; i += NT) thist[i] = 0u;
    for (int b = tid; b <= NBUK; b += NT) {
        int lo2 = 0, hi2 = NB;                // lower_bound(ebuk, b)
        #pragma unroll
        for (int it = 0; it < 7; ++it) {
            if (lo2 < hi2) {
                int mid = (lo2 + hi2) >> 1;
                if ((int)ebuk[mid] < b) lo2 = mid + 1; else hi2 = mid;
            }
        }
        arr[b] = (unsigned)lo2;
    }
    __syncthreads();

    // ---- bin all elements via bucket LUT: edges in buckets<b are <=v,
    //      buckets>b are >v; only same-bucket edges need comparing ----
    int bl[EPT];
    #pragma unroll
    for (int u = 0; u < EPT; ++u) {
        int b   = bucket_of(v[u]);
        int cnt = (int)arr[b];
        int en  = (int)arr[b + 1];
        for (int j = cnt; j < en; ++j) cnt += (edges[j] <= v[u]);
        bl[u] = min(cnt, NB - 1);
    }
    if (lane == 0) wfirst[wid] = bl[0];
    __syncthreads();

    // ---- transition histogram over 8191 consecutive pairs ----
    int nxt0 = __shfl_down(bl[0], 1);
    if (lane == 63 && wid < 7) nxt0 = wfirst[wid + 1];
    #pragma unroll
    for (int u = 0; u + 1 < EPT; ++u)
        atomicAdd(&thist[bl[u] * NB + bl[u + 1]], 1u);
    if (tid + 1 < NT)
        atomicAdd(&thist[bl[EPT - 1] * NB + nxt0], 1u);
    __syncthreads();

    // ---- write out: hist / (L-1) ----
    float* __restrict__ orow = out + (size_t)row * (NB * NB);
    for (int i = tid; i < NB * NB; i += NT)
        orow[i] = __fdiv_rn((float)thist[i], (float)(LROW - 1));
}

extern "C" void kernel_launch(void* const* d_in, const int* in_sizes, int n_in,
                              void* d_out, int out_size, void* d_ws, size_t ws_size,
                              hipStream_t stream) {
    const float* x = (const float*)d_in[0];
    float* out = (float*)d_out;
    const int rows = in_sizes[0] / LROW;   // N*C = 2048
    mtf_kernel<<<rows, NT, 0, stream>>>(x, out);
}

// Round 10
// 166.687 us; speedup vs baseline: 1.1189x; 1.0443x over previous
//
#include <hip/hip_runtime.h>
#include <cfloat>

constexpr int NB   = 65;      // N_BINS (= OUTPUT_SIZE)
constexpr int LROW = 8192;    // L
constexpr int NT   = 512;     // threads per block
constexpr int EPT  = 16;      // elements per thread
constexpr int NBUK = 1024;    // value buckets for multiselect

// Monotone bucket map: v -> [0, NBUK). Equal v -> equal bucket. Clamping is
// monotone, so correctness never depends on the [-6,6] range assumption.
// ~4 VALU; ALWAYS recompute (caching 16 of these spilled to scratch in r8).
__device__ __forceinline__ int bucket_of(float v) {
    float t = (v + 6.0f) * (float(NBUK) / 12.0f);
    t = fminf(fmaxf(t, 0.0f), float(NBUK - 1));
    return (int)t;
}

struct ERange { unsigned short stL, enL, stH, enH; };   // pre-scatter bucket ranges

__global__ __launch_bounds__(NT, 8) void mtf_kernel(const float* __restrict__ x,
                                                    float* __restrict__ out) {
    __shared__ __align__(16) float vals[LROW];          // 32 KB: interesting-bucket values; later aliased as hist
    __shared__ __align__(16) unsigned int arr[NBUK + 1];// counts -> excl prefix (arr[NBUK]=m) -> consumed -> edge LUT
    __shared__ unsigned int tops[64];                   // arr[16i+16]: level-1 for 64-ary rank search
    __shared__ float edges[NB];
    __shared__ unsigned short ebuk[NB];                 // bucket of each edge (sorted)
    __shared__ ERange erng[NB];                         // per-edge bucket ranges (recorded pre-scatter)
    __shared__ unsigned int bmap[NBUK / 32];            // interesting-bucket bitmap
    __shared__ unsigned int wsum[8];
    __shared__ int wfirst[8];
    __shared__ int s_first, s_last;

    const int row  = blockIdx.x;          // n*C + c
    const int tid  = threadIdx.x;
    const int lane = tid & 63;
    const int wid  = tid >> 6;
    const float* __restrict__ xr = x + (size_t)row * LROW;

    if (tid == 0) { s_first = LROW; s_last = -1; }
    #pragma unroll
    for (int q = 0; q < NBUK / NT; ++q) arr[tid + q * NT] = 0u;
    if (tid < NBUK / 32) bmap[tid] = 0u;

    // ---- load 16 contiguous elements into registers ----
    float v[EPT];
    const int base = tid * EPT;
    #pragma unroll
    for (int q = 0; q < 4; ++q) {
        float4 t = *reinterpret_cast<const float4*>(xr + base + q * 4);
        v[q*4+0] = t.x; v[q*4+1] = t.y; v[q*4+2] = t.z; v[q*4+3] = t.w;
    }

    // ---- first/last nonzero: thread -> wave-reduce -> one atomic per wave ----
    int lfirst = LROW, llast = -1;
    #pragma unroll
    for (int u = 0; u < EPT; ++u)
        if (v[u] != 0.0f) { lfirst = min(lfirst, base + u); llast = max(llast, base + u); }
    #pragma unroll
    for (int d = 32; d > 0; d >>= 1) {
        lfirst = min(lfirst, __shfl_xor(lfirst, d));
        llast  = max(llast,  __shfl_xor(llast,  d));
    }
    __syncthreads();                      // init visible before atomics
    if (lane == 0 && llast >= 0) { atomicMin(&s_first, lfirst); atomicMax(&s_last, llast); }
    __syncthreads();
    const int first = s_first, last = s_last;
    const int m = (last >= 0) ? (last - first + 1) : 0;   // mask.sum()

    // ---- bucket counts (masked elements never placed; ranks only reach m-1) ----
    if (m > 0) {
        #pragma unroll
        for (int u = 0; u < EPT; ++u) {
            int idx = base + u;
            if (idx >= first && idx <= last) atomicAdd(&arr[bucket_of(v[u])], 1u);
        }
    }
    __syncthreads();

    // ---- in-place exclusive scan of arr[0..NBUK); arr[NBUK]=m ----
    {
        uint2 c = *reinterpret_cast<uint2*>(&arr[tid * 2]);
        unsigned own = c.x + c.y;
        unsigned inc = own;
        #pragma unroll
        for (int d = 1; d < 64; d <<= 1) {
            unsigned n = __shfl_up(inc, d);
            if (lane >= d) inc += n;
        }
        if (lane == 63) wsum[wid] = inc;
        __syncthreads();
        if (wid == 0) {
            unsigned t0 = (lane < 8) ? wsum[lane] : 0u;
            unsigned sc = t0;
            #pragma unroll
            for (int d = 1; d < 8; d <<= 1) {
                unsigned n = __shfl_up(sc, d);
                if (lane >= d) sc += n;
            }
            if (lane < 8) wsum[lane] = sc - t0;
        }
        __syncthreads();
        unsigned b0 = wsum[wid] + (inc - own);
        arr[tid*2+0] = b0;
        arr[tid*2+1] = b0 + c.x;
        if (tid == NT - 1) arr[NBUK] = b0 + own;          // total = m
    }
    __syncthreads();
    if (tid < 64) tops[tid] = arr[tid * 16 + 16];         // ends of bucket 16i+15
    __syncthreads();

    // ---- E1: rank->bucket searches on the PREFIX array; record ranges;
    //      mark interesting buckets (ranks depend only on m) ----
    const float delta = __fdiv_rn(1.0f, 65.0f);           // fl(1/65), matches linspace
    for (int k = wid; k < NB; k += 8) {
        if (m == 0) continue;
        float qv  = __fmul_rn((float)k, delta);
        float pos = __fmul_rn(qv, (float)(m - 1));
        int lo = (int)floorf(pos);
        int hi = (int)ceilf(pos);
        // smallest b with prefix[b+1] > r  (element of rank r lives in b)
        int bL, bH;
        {
            unsigned long long b1 = __ballot((int)tops[lane] > lo);  // tops[63]=m>lo
            int seg = __ffsll(b1) - 1;
            unsigned long long b2 = __ballot(lane < 16 && (int)arr[seg*16 + lane + 1] > lo);
            bL = seg * 16 + __ffsll(b2) - 1;
        }
        if (hi == lo) bH = bL;
        else {
            unsigned long long b1 = __ballot((int)tops[lane] > hi);
            int seg = __ffsll(b1) - 1;
            unsigned long long b2 = __ballot(lane < 16 && (int)arr[seg*16 + lane + 1] > hi);
            bH = seg * 16 + __ffsll(b2) - 1;
        }
        if (lane == 0) {
            ERange e;
            e.stL = (unsigned short)arr[bL]; e.enL = (unsigned short)arr[bL + 1];
            e.stH = (unsigned short)arr[bH]; e.enH = (unsigned short)arr[bH + 1];
            erng[k] = e;
            atomicOr(&bmap[bL >> 5], 1u << (bL & 31));
            atomicOr(&bmap[bH >> 5], 1u << (bH & 31));
        }
    }
    __syncthreads();

    // ---- sparse scatter: only elements in interesting buckets (~10-15%) ----
    if (m > 0) {
        #pragma unroll
        for (int u = 0; u < EPT; ++u) {
            int idx = base + u;
            if (idx >= first && idx <= last) {
                int b = bucket_of(v[u]);
                if ((bmap[b >> 5] >> (b & 31)) & 1u) {
                    unsigned slot = atomicAdd(&arr[b], 1u);   // consume prefix
                    vals[slot] = v[u];
                }
            }
        }
    }
    __syncthreads();

    // ---- E2: per-edge 64-lane in-register bitonic sort + rank extraction ----
    // q = vlo + frac*(vhi-vlo): separate _rn ops, no FMA (matches JAX f32).
    for (int k = wid; k < NB; k += 8) {
        if (m == 0) {
            if (lane == 0) { edges[k] = 0.0f; ebuk[k] = (unsigned short)bucket_of(0.0f); }
            continue;
        }
        float qv   = __fmul_rn((float)k, delta);
        float pos  = __fmul_rn(qv, (float)(m - 1));
        float flo  = floorf(pos);
        float frac = __fsub_rn(pos, flo);
        int lo = (int)flo;
        int hi = (int)ceilf(pos);
        ERange e = erng[k];
        int stL = e.stL, enL = e.enL;
        int s   = enL - stL;
        int rlo = lo - stL, rhi = hi - stL;
        bool sameB = (e.stH == e.stL);        // bH==bL (distinct buckets have distinct starts)
        float vlo = 0.0f, vhi = 0.0f;

        if (s <= 64) {
            // gather bucket into one value per lane (pad +inf), bitonic sort
            int gi = stL + lane;
            float val = (gi < enL) ? vals[gi] : FLT_MAX;
            #pragma unroll
            for (int kk = 2; kk <= 64; kk <<= 1) {
                #pragma unroll
                for (int jj = kk >> 1; jj > 0; jj >>= 1) {
                    float o = __shfl_xor(val, jj);
                    bool keepmin = (((lane & jj) == 0) == ((lane & kk) == 0));
                    float mn = fminf(val, o), mx = fmaxf(val, o);
                    val = keepmin ? mn : mx;
                }
            }
            vlo = __shfl(val, rlo);
            vhi = sameB ? ((hi == lo) ? vlo : __shfl(val, rhi)) : 0.0f;
        } else {
            // fallback: counting selection (rare; any distribution)
            bool fL = false, fH = !sameB;
            for (int b0 = stL; b0 < enL; b0 += 64) {
                int i = b0 + lane;
                bool act = i < enL;
                float vi = act ? vals[i] : 0.0f;
                int cl = 0, ce = 0;
                for (int j = stL; j < enL; ++j) {
                    float vj = vals[j];
                    cl += (vj < vi);
                    ce += (vj == vi);
                }
                if (!fL) {
                    unsigned long long mk = __ballot(act && cl <= rlo && rlo < cl + ce);
                    if (mk) { vlo = __shfl(vi, __ffsll(mk) - 1); fL = true; }
                }
                if (!fH) {
                    unsigned long long mk = __ballot(act && cl <= rhi && rhi < cl + ce);
                    if (mk) { vhi = __shfl(vi, __ffsll(mk) - 1); fH = true; }
                }
                if (fL && fH) break;
            }
        }
        if (!sameB) {
            // hi's in-bucket rank is 0 by prefix continuity -> bucket minimum
            float mn = FLT_MAX;
            for (int i = e.stH + lane; i < e.enH; i += 64) mn = fminf(mn, vals[i]);
            #pragma unroll
            for (int d = 32; d > 0; d >>= 1) mn = fminf(mn, __shfl_xor(mn, d));
            vhi = mn;
        }
        float ev = __fadd_rn(vlo, __fmul_rn(frac, __fsub_rn(vhi, vlo)));
        if (lane == 0) { edges[k] = ev; ebuk[k] = (unsigned short)bucket_of(ev); }
    }
    __syncthreads();

    // ---- build L[b] = #edges in buckets < b (arr dead -> reuse);
    //      zero the transition hist (vals dead -> alias) ----
    unsigned int* thist = reinterpret_cast<unsigned int*>(vals);
    for (int i = tid; i < NB * NB; i += NT) thist[i] = 0u;
    for (int b = tid; b <= NBUK; b += NT) {
        int lo2 = 0, hi2 = NB;                // lower_bound(ebuk, b)
        #pragma unroll
        for (int it = 0; it < 7; ++it) {
            if (lo2 < hi2) {
                int mid = (lo2 + hi2) >> 1;
                if ((int)ebuk[mid] < b) lo2 = mid + 1; else hi2 = mid;
            }
        }
        arr[b] = (unsigned)lo2;
    }
    __syncthreads();

    // ---- bin all elements via bucket LUT: edges in buckets<b are <=v,
    //      buckets>b are >v; only same-bucket edges need comparing ----
    int bl[EPT];
    #pragma unroll
    for (int u = 0; u < EPT; ++u) {
        int b   = bucket_of(v[u]);
        int cnt = (int)arr[b];
        int en  = (int)arr[b + 1];
        for (int j = cnt; j < en; ++j) cnt += (edges[j] <= v[u]);
        bl[u] = min(cnt, NB - 1);
    }
    if (lane == 0) wfirst[wid] = bl[0];
    __syncthreads();

    // ---- transition histogram over 8191 consecutive pairs ----
    int nxt0 = __shfl_down(bl[0], 1);
    if (lane == 63 && wid < 7) nxt0 = wfirst[wid + 1];
    #pragma unroll
    for (int u = 0; u + 1 < EPT; ++u)
        atomicAdd(&thist[bl[u] * NB + bl[u + 1]], 1u);
    if (tid + 1 < NT)
        atomicAdd(&thist[bl[EPT - 1] * NB + nxt0], 1u);
    __syncthreads();

    // ---- write out: hist / (L-1) ----
    float* __restrict__ orow = out + (size_t)row * (NB * NB);
    for (int i = tid; i < NB * NB; i += NT)
        orow[i] = __fdiv_rn((float)thist[i], (float)(LROW - 1));
}

extern "C" void kernel_launch(void* const* d_in, const int* in_sizes, int n_in,
                              void* d_out, int out_size, void* d_ws, size_t ws_size,
                              hipStream_t stream) {
    const float* x = (const float*)d_in[0];
    float* out = (float*)d_out;
    const int rows = in_sizes[0] / LROW;   // N*C = 2048
    mtf_kernel<<<rows, NT, 0, stream>>>(x, out);
}

// Round 11
// 162.531 us; speedup vs baseline: 1.1475x; 1.0256x over previous
//
#include <hip/hip_runtime.h>
#include <cfloat>

constexpr int NB   = 65;      // N_BINS (= OUTPUT_SIZE)
constexpr int LROW = 8192;    // L
constexpr int NT   = 512;     // threads per block
constexpr int EPT  = 16;      // elements per thread
constexpr int NBUK = 1024;    // value buckets for multiselect

// Monotone bucket map: v -> [0, NBUK). Equal v -> equal bucket. Clamping is
// monotone, so correctness never depends on the [-6,6] range assumption.
// ~4 VALU; ALWAYS recompute (caching 16 of these spilled to scratch in r8).
__device__ __forceinline__ int bucket_of(float v) {
    float t = (v + 6.0f) * (float(NBUK) / 12.0f);
    t = fminf(fmaxf(t, 0.0f), float(NBUK - 1));
    return (int)t;
}

// Lane-exchange val with lane^J using the cheapest path per distance:
// J=1,2: DPP quad_perm (pure VALU). J=4,8,16: ds_swizzle immediate pattern
// (no address setup; xor-mask<32 stays within the 32-lane group). J=32: shfl.
template<int J>
__device__ __forceinline__ float lxor(float v) {
    if constexpr (J == 1)
        return __int_as_float(__builtin_amdgcn_mov_dpp(__float_as_int(v), 0xB1, 0xF, 0xF, true)); // quad_perm [1,0,3,2]
    else if constexpr (J == 2)
        return __int_as_float(__builtin_amdgcn_mov_dpp(__float_as_int(v), 0x4E, 0xF, 0xF, true)); // quad_perm [2,3,0,1]
    else if constexpr (J == 4)
        return __int_as_float(__builtin_amdgcn_ds_swizzle(__float_as_int(v), 0x101F)); // xor 4
    else if constexpr (J == 8)
        return __int_as_float(__builtin_amdgcn_ds_swizzle(__float_as_int(v), 0x201F)); // xor 8
    else if constexpr (J == 16)
        return __int_as_float(__builtin_amdgcn_ds_swizzle(__float_as_int(v), 0x401F)); // xor 16
    else
        return __shfl_xor(v, 32);
}

// One bitonic compare-exchange step: ascending iff (lane&K)==0.
template<int K, int J>
__device__ __forceinline__ void cex(float& val, int lane) {
    float o = lxor<J>(val);
    bool keepmin = (((lane & J) == 0) == ((lane & K) == 0));
    float mn = fminf(val, o), mx = fmaxf(val, o);
    val = keepmin ? mn : mx;
}

struct ERange { unsigned short stL, enL, stH, enH; };   // pre-scatter bucket ranges

__global__ __launch_bounds__(NT, 8) void mtf_kernel(const float* __restrict__ x,
                                                    float* __restrict__ out) {
    __shared__ __align__(16) float vals[LROW];          // 32 KB: bucket values; later thist (4225 w) + elut (@4352)
    __shared__ __align__(16) unsigned int arr[NBUK + 1];// counts -> excl prefix (arr[NBUK]=m) -> consumed
    __shared__ unsigned int tops[64];                   // arr[16i+16]: level-1 for 64-ary rank search
    __shared__ float edges[NB];
    __shared__ unsigned short ebuk[NB];                 // bucket of each edge (sorted)
    __shared__ ERange erng[NB];                         // per-edge bucket ranges (recorded pre-scatter)
    __shared__ unsigned int bmap[NBUK / 32];            // interesting-bucket bitmap
    __shared__ unsigned int wsum[8];
    __shared__ int wfirst[8];
    __shared__ int s_first, s_last;

    const int row  = blockIdx.x;          // n*C + c
    const int tid  = threadIdx.x;
    const int lane = tid & 63;
    const int wid  = tid >> 6;
    const float* __restrict__ xr = x + (size_t)row * LROW;

    if (tid == 0) { s_first = LROW; s_last = -1; }
    #pragma unroll
    for (int q = 0; q < NBUK / NT; ++q) arr[tid + q * NT] = 0u;
    if (tid < NBUK / 32) bmap[tid] = 0u;

    // ---- load 16 contiguous elements into registers ----
    float v[EPT];
    const int base = tid * EPT;
    #pragma unroll
    for (int q = 0; q < 4; ++q) {
        float4 t = *reinterpret_cast<const float4*>(xr + base + q * 4);
        v[q*4+0] = t.x; v[q*4+1] = t.y; v[q*4+2] = t.z; v[q*4+3] = t.w;
    }

    // ---- first/last nonzero: thread -> wave-reduce -> one atomic per wave ----
    int lfirst = LROW, llast = -1;
    #pragma unroll
    for (int u = 0; u < EPT; ++u)
        if (v[u] != 0.0f) { lfirst = min(lfirst, base + u); llast = max(llast, base + u); }
    #pragma unroll
    for (int d = 32; d > 0; d >>= 1) {
        lfirst = min(lfirst, __shfl_xor(lfirst, d));
        llast  = max(llast,  __shfl_xor(llast,  d));
    }
    __syncthreads();                      // init visible before atomics
    if (lane == 0 && llast >= 0) { atomicMin(&s_first, lfirst); atomicMax(&s_last, llast); }
    __syncthreads();
    const int first = s_first, last = s_last;
    const int m = (last >= 0) ? (last - first + 1) : 0;   // mask.sum()

    // ---- bucket counts (masked elements never placed; ranks only reach m-1) ----
    if (m > 0) {
        #pragma unroll
        for (int u = 0; u < EPT; ++u) {
            int idx = base + u;
            if (idx >= first && idx <= last) atomicAdd(&arr[bucket_of(v[u])], 1u);
        }
    }
    __syncthreads();

    // ---- in-place exclusive scan of arr[0..NBUK); arr[NBUK]=m ----
    {
        uint2 c = *reinterpret_cast<uint2*>(&arr[tid * 2]);
        unsigned own = c.x + c.y;
        unsigned inc = own;
        #pragma unroll
        for (int d = 1; d < 64; d <<= 1) {
            unsigned n = __shfl_up(inc, d);
            if (lane >= d) inc += n;
        }
        if (lane == 63) wsum[wid] = inc;
        __syncthreads();
        if (wid == 0) {
            unsigned t0 = (lane < 8) ? wsum[lane] : 0u;
            unsigned sc = t0;
            #pragma unroll
            for (int d = 1; d < 8; d <<= 1) {
                unsigned n = __shfl_up(sc, d);
                if (lane >= d) sc += n;
            }
            if (lane < 8) wsum[lane] = sc - t0;
        }
        __syncthreads();
        unsigned b0 = wsum[wid] + (inc - own);
        arr[tid*2+0] = b0;
        arr[tid*2+1] = b0 + c.x;
        if (tid == NT - 1) arr[NBUK] = b0 + own;          // total = m
    }
    __syncthreads();
    if (tid < 64) tops[tid] = arr[tid * 16 + 16];         // ends of bucket 16i+15
    __syncthreads();

    // ---- E1: rank->bucket searches on the PREFIX array; record ranges;
    //      mark interesting buckets (ranks depend only on m) ----
    const float delta = __fdiv_rn(1.0f, 65.0f);           // fl(1/65), matches linspace
    for (int k = wid; k < NB; k += 8) {
        if (m == 0) continue;
        float qv  = __fmul_rn((float)k, delta);
        float pos = __fmul_rn(qv, (float)(m - 1));
        int lo = (int)floorf(pos);
        int hi = (int)ceilf(pos);
        // smallest b with prefix[b+1] > r  (element of rank r lives in b)
        int bL, bH;
        {
            unsigned long long b1 = __ballot((int)tops[lane] > lo);  // tops[63]=m>lo
            int seg = __ffsll(b1) - 1;
            unsigned long long b2 = __ballot(lane < 16 && (int)arr[seg*16 + lane + 1] > lo);
            bL = seg * 16 + __ffsll(b2) - 1;
        }
        if (hi == lo) bH = bL;
        else {
            unsigned long long b1 = __ballot((int)tops[lane] > hi);
            int seg = __ffsll(b1) - 1;
            unsigned long long b2 = __ballot(lane < 16 && (int)arr[seg*16 + lane + 1] > hi);
            bH = seg * 16 + __ffsll(b2) - 1;
        }
        if (lane == 0) {
            ERange e;
            e.stL = (unsigned short)arr[bL]; e.enL = (unsigned short)arr[bL + 1];
            e.stH = (unsigned short)arr[bH]; e.enH = (unsigned short)arr[bH + 1];
            erng[k] = e;
            atomicOr(&bmap[bL >> 5], 1u << (bL & 31));
            atomicOr(&bmap[bH >> 5], 1u << (bH & 31));
        }
    }
    __syncthreads();

    // ---- sparse scatter: only elements in interesting buckets (~10-15%) ----
    if (m > 0) {
        #pragma unroll
        for (int u = 0; u < EPT; ++u) {
            int idx = base + u;
            if (idx >= first && idx <= last) {
                int b = bucket_of(v[u]);
                if ((bmap[b >> 5] >> (b & 31)) & 1u) {
                    unsigned slot = atomicAdd(&arr[b], 1u);   // consume prefix
                    vals[slot] = v[u];
                }
            }
        }
    }
    __syncthreads();

    // ---- E2: per-edge 64-lane in-register bitonic sort (cheap shuffles) ----
    // q = vlo + frac*(vhi-vlo): separate _rn ops, no FMA (matches JAX f32).
    for (int k = wid; k < NB; k += 8) {
        if (m == 0) {
            if (lane == 0) { edges[k] = 0.0f; ebuk[k] = (unsigned short)bucket_of(0.0f); }
            continue;
        }
        float qv   = __fmul_rn((float)k, delta);
        float pos  = __fmul_rn(qv, (float)(m - 1));
        float flo  = floorf(pos);
        float frac = __fsub_rn(pos, flo);
        int lo = (int)flo;
        int hi = (int)ceilf(pos);
        ERange e = erng[k];
        int stL = e.stL, enL = e.enL;
        int s   = enL - stL;
        int rlo = lo - stL, rhi = hi - stL;
        bool sameB = (e.stH == e.stL);        // bH==bL (distinct buckets have distinct starts)
        float vlo = 0.0f, vhi = 0.0f;

        if (s <= 64) {
            // gather bucket into one value per lane (pad +inf), bitonic sort
            int gi = stL + lane;
            float val = (gi < enL) ? vals[gi] : FLT_MAX;
            cex<2,1>(val, lane);
            cex<4,2>(val, lane);  cex<4,1>(val, lane);
            cex<8,4>(val, lane);  cex<8,2>(val, lane);  cex<8,1>(val, lane);
            cex<16,8>(val, lane); cex<16,4>(val, lane); cex<16,2>(val, lane); cex<16,1>(val, lane);
            cex<32,16>(val, lane); cex<32,8>(val, lane); cex<32,4>(val, lane); cex<32,2>(val, lane); cex<32,1>(val, lane);
            cex<64,32>(val, lane); cex<64,16>(val, lane); cex<64,8>(val, lane); cex<64,4>(val, lane); cex<64,2>(val, lane); cex<64,1>(val, lane);
            vlo = __shfl(val, rlo);
            vhi = sameB ? ((hi == lo) ? vlo : __shfl(val, rhi)) : 0.0f;
        } else {
            // fallback: counting selection (rare; any distribution)
            bool fL = false, fH = !sameB;
            for (int b0 = stL; b0 < enL; b0 += 64) {
                int i = b0 + lane;
                bool act = i < enL;
                float vi = act ? vals[i] : 0.0f;
                int cl = 0, ce = 0;
                for (int j = stL; j < enL; ++j) {
                    float vj = vals[j];
                    cl += (vj < vi);
                    ce += (vj == vi);
                }
                if (!fL) {
                    unsigned long long mk = __ballot(act && cl <= rlo && rlo < cl + ce);
                    if (mk) { vlo = __shfl(vi, __ffsll(mk) - 1); fL = true; }
                }
                if (!fH) {
                    unsigned long long mk = __ballot(act && cl <= rhi && rhi < cl + ce);
                    if (mk) { vhi = __shfl(vi, __ffsll(mk) - 1); fH = true; }
                }
                if (fL && fH) break;
            }
        }
        if (!sameB) {
            // hi's in-bucket rank is 0 by prefix continuity -> bucket minimum
            float mn = FLT_MAX;
            for (int i = e.stH + lane; i < e.enH; i += 64) mn = fminf(mn, vals[i]);
            #pragma unroll
            for (int d = 32; d > 0; d >>= 1) mn = fminf(mn, __shfl_xor(mn, d));
            vhi = mn;
        }
        float ev = __fadd_rn(vlo, __fmul_rn(frac, __fsub_rn(vhi, vlo)));
        if (lane == 0) { edges[k] = ev; ebuk[k] = (unsigned short)bucket_of(ev); }
    }
    __syncthreads();

    // ---- zero the transition hist (vals dead -> alias) and build the packed
    //      binning LUT elut[b] = L[b] | (L[b+1]-L[b])<<8 in vals' dead tail ----
    unsigned int* thist = reinterpret_cast<unsigned int*>(vals);
    unsigned short* elut = reinterpret_cast<unsigned short*>(vals + 4352);  // 4225 words used by thist
    for (int i = tid; i < NB * NB; i += NT) thist[i] = 0u;
    for (int b = tid; b < NBUK; b += NT) {
        int l0, l1;
        {   int lo2 = 0, hi2 = NB;            // lower_bound(ebuk, b)
            #pragma unroll
            for (int it = 0; it < 7; ++it)
                if (lo2 < hi2) { int mid = (lo2 + hi2) >> 1; if ((int)ebuk[mid] < b) lo2 = mid + 1; else hi2 = mid; }
            l0 = lo2;
        }
        {   int lo2 = 0, hi2 = NB;            // lower_bound(ebuk, b+1)
            #pragma unroll
            for (int it = 0; it < 7; ++it)
                if (lo2 < hi2) { int mid = (lo2 + hi2) >> 1; if ((int)ebuk[mid] < b + 1) lo2 = mid + 1; else hi2 = mid; }
            l1 = lo2;
        }
        elut[b] = (unsigned short)(l0 | ((l1 - l0) << 8));
    }
    __syncthreads();

    // ---- bin all elements: edges in buckets<b are <=v, buckets>b are >v;
    //      only same-bucket edges need comparing (usually none) ----
    int bl[EPT];
    #pragma unroll
    for (int u = 0; u < EPT; ++u) {
        int b = bucket_of(v[u]);
        unsigned lu = elut[b];
        int e0 = (int)(lu & 0xFFu);
        int n  = (int)(lu >> 8);
        int cnt = e0;
        for (int j = e0; j < e0 + n; ++j) cnt += (edges[j] <= v[u]);
        bl[u] = min(cnt, NB - 1);
    }
    if (lane == 0) wfirst[wid] = bl[0];
    __syncthreads();

    // ---- transition histogram over 8191 consecutive pairs ----
    int nxt0 = __shfl_down(bl[0], 1);
    if (lane == 63 && wid < 7) nxt0 = wfirst[wid + 1];
    #pragma unroll
    for (int u = 0; u + 1 < EPT; ++u)
        atomicAdd(&thist[bl[u] * NB + bl[u + 1]], 1u);
    if (tid + 1 < NT)
        atomicAdd(&thist[bl[EPT - 1] * NB + nxt0], 1u);
    __syncthreads();

    // ---- write out: hist / (L-1) ----
    float* __restrict__ orow = out + (size_t)row * (NB * NB);
    for (int i = tid; i < NB * NB; i += NT)
        orow[i] = __fdiv_rn((float)thist[i], (float)(LROW - 1));
}

extern "C" void kernel_launch(void* const* d_in, const int* in_sizes, int n_in,
                              void* d_out, int out_size, void* d_ws, size_t ws_size,
                              hipStream_t stream) {
    const float* x = (const float*)d_in[0];
    float* out = (float*)d_out;
    const int rows = in_sizes[0] / LROW;   // N*C = 2048
    mtf_kernel<<<rows, NT, 0, stream>>>(x, out);
}